// Round 6
// baseline (818990.869 us; speedup 1.0000x reference)
//
#include <hip/hip_runtime.h>

typedef unsigned short u16;

#define NWG 256
#define NT  256
#define TS  512
#define HD  1024
#define BS  128
#define NI  64
#define NO  64
#define XR  16      // batch rows per XCD
#define CC  32      // hidden cols per CU
#define RCP 17      // redC padded row stride (breaks 4-way bank conflict)

typedef __attribute__((ext_vector_type(8))) short bf16x8;
typedef __attribute__((ext_vector_type(4))) float f32x4;

__device__ __forceinline__ float bf2f(u16 u) {
    union { unsigned int i; float f; } v; v.i = ((unsigned int)u) << 16; return v.f;
}
__device__ __forceinline__ u16 f2bf(float f) {
    union { float fl; unsigned int i; } v; v.fl = f;
    unsigned int x = v.i;
    return (u16)((x + 0x7fffu + ((x >> 16) & 1u)) >> 16);  // RNE, finite inputs
}
__device__ __forceinline__ float ldv(const void* p, size_t i, bool isf32) {
    return isf32 ? ((const float*)p)[i] : bf2f(((const u16*)p)[i]);
}

// L2-executed atomic returning old value (sc0). Used at init (ticket claim) and
// as the poll *fallback* (round-4-proven visibility path).
__device__ __forceinline__ unsigned l2_atomic_add(unsigned* p, unsigned v) {
    unsigned old;
    asm volatile("global_atomic_add %0, %1, %2, off sc0\n\t"
                 "s_waitcnt vmcnt(0)"
                 : "=&v"(old) : "v"(p), "v"(v) : "memory");
    return old;
}

// Poll read: plain load with sc0 (L1 bypass -> served from the XCD-local L2).
// No RMW -> no L2-bank serialization, no HBM write-through (round-4 lesson:
// atomic polls wrote 1.4 GB to HBM and queued the publisher behind the RMWs).
__device__ __forceinline__ unsigned l2_load(const unsigned* p) {
    unsigned v;
    asm volatile("global_load_dword %0, %1, off sc0\n\t"
                 "s_waitcnt vmcnt(0)"
                 : "=v"(v) : "v"(p) : "memory");
    return v;
}
// Publish: plain store with sc0. Single writer per flag, monotonic values, so a
// store (not RMW) suffices. Preceded by __syncthreads() whose per-wave
// s_waitcnt vmcnt(0) guarantees all h-stores are already acked by L2.
__device__ __forceinline__ void l2_store(unsigned* p, unsigned v) {
    asm volatile("global_store_dword %0, %1, off sc0\n\t"
                 "s_waitcnt vmcnt(0)"
                 :: "v"(p), "v"(v) : "memory");
}

// Wave-0-only spin on the 32 per-CU flags of this XCD (2 lanes per flag).
// Fast path: plain sc0 loads. Liveness fallback: if ~16K spins (~2 ms; normal
// inter-CU skew is <1 us) pass without progress, switch to atomic-add(0) reads
// -- the exact mechanism round 4 ran correctly with. Guarantees termination
// even if plain-load visibility stalls (round-5 hang hypothesis).
__device__ __forceinline__ void wait_flags_w0(const unsigned* qbase, int lane, unsigned target) {
    const unsigned* p = qbase + (lane & 31) * 16;
    for (int spins = 0; spins < (1 << 14); ++spins) {
        unsigned f = l2_load(p);
        if (__all((int)(f >= target))) return;
        __builtin_amdgcn_s_sleep(1);
    }
    for (;;) {   // fallback (should never engage)
        unsigned f = l2_atomic_add((unsigned*)p, 0u);
        if (__all((int)(f >= target))) return;
        __builtin_amdgcn_s_sleep(8);
    }
}

// 8 A-fragments (one K-quarter) via sc0 loads (L1 bypass -> XCD L2, where peer
// CUs' write-through stores live).
__device__ __forceinline__ void load_a_frags(const u16* ap, bf16x8* a) {
    asm volatile(
        "global_load_dwordx4 %0, %8, off sc0\n\t"
        "global_load_dwordx4 %1, %8, off offset:64 sc0\n\t"
        "global_load_dwordx4 %2, %8, off offset:128 sc0\n\t"
        "global_load_dwordx4 %3, %8, off offset:192 sc0\n\t"
        "global_load_dwordx4 %4, %8, off offset:256 sc0\n\t"
        "global_load_dwordx4 %5, %8, off offset:320 sc0\n\t"
        "global_load_dwordx4 %6, %8, off offset:384 sc0\n\t"
        "global_load_dwordx4 %7, %8, off offset:448 sc0\n\t"
        "s_waitcnt vmcnt(0)"
        : "=&v"(a[0]), "=&v"(a[1]), "=&v"(a[2]), "=&v"(a[3]),
          "=&v"(a[4]), "=&v"(a[5]), "=&v"(a[6]), "=&v"(a[7])
        : "v"(ap) : "memory");
}

// LDS ~156KB -> exactly 1 WG/CU; cooperative launch => all 256 WGs co-resident
// => every XCD hosts exactly 32 WGs. WGs self-identify their XCD via
// s_getreg(HW_REG_XCC_ID) + per-XCD ticket; all hot-loop flag/hidden traffic is
// XCD-local (one shared L2; no fences, no hot-loop atomics, no L3 round-trips).
__global__ __launch_bounds__(NT)
void arnn_xcd(const void* __restrict__ xv,
              const void* __restrict__ encwv,
              const void* __restrict__ encbv,
              const void* __restrict__ recwv,
              const void* __restrict__ fgtwv,
              const void* __restrict__ decwv,
              const void* __restrict__ decbv,
              const void* __restrict__ hinitwv,
              const void* __restrict__ hinitbv,
              void* __restrict__ outv,
              u16* __restrict__ h0buf,
              u16* __restrict__ h1buf,
              unsigned* __restrict__ tickets,
              unsigned* __restrict__ flags)
{
    // WB: 4 n-tiles of 16 cols in MFMA B-frag lane order.
    // tile0: rec cols j0..j0+15, 34 k-steps (32 rec K=1024 + 2 enc K=64)
    // tile1: rec cols j0+16..j0+31, 34 k-steps
    // tile2/3: fgt cols, 32 k-steps. Entry: WB[(tb+ks)*64 + lane][8].
    __shared__ short WB[132 * 64 * 8];          // 135168 B
    __shared__ float redC[4 * 5 * 16 * RCP];    // 21760 B: [kq][tile(4=dec)][row][col], padded
    __shared__ float hst[XR * CC];              // fp32 master hidden slice
    __shared__ float encbS[CC];
    __shared__ float decbLS[16];
    __shared__ unsigned s_xcd, s_slot;
    __shared__ int s_f32;

    const int tid  = threadIdx.x;
    const int wave = tid >> 6;
    const int lane = tid & 63;
    const int m    = lane & 15;      // C row / A row (batch-local)
    const int quad = lane >> 4;      // k-subblock within K=32

    // ---- identify XCD, claim per-XCD CU slot ----
    if (tid == 0) {
        unsigned xcc;
        asm volatile("s_getreg_b32 %0, hwreg(HW_REG_XCC_ID, 0, 4)" : "=s"(xcc));
        xcc &= 7u;
        unsigned slot = l2_atomic_add(tickets + xcc * 16, 1u);
        s_xcd = xcc;
        s_slot = slot & 31u;
        s_f32 = 0;
    }
    __syncthreads();
    { // runtime dtype detection on rec_w raw bits (round-1 post-mortem)
        float v = bf2f(((const u16*)recwv)[tid]);
        if (!(v >= -1.0f && v <= 1.0f)) s_f32 = 1;
    }
    __syncthreads();
    const bool isf32 = (s_f32 != 0);
    const int xcd  = (int)s_xcd;
    const int slot = (int)s_slot;
    const int b0   = xcd * XR;       // this XCD's batch rows
    const int j0   = slot * CC;      // this CU's hidden cols
    const int dt   = slot & 3;       // dec tile: out cols 16dt..16dt+15
    unsigned* qbase  = flags + xcd * 32 * 16;
    unsigned* myflag = qbase + slot * 16;

    // ---- stage weights into LDS in B-frag order ----
    for (int idx = tid; idx < 132 * 64; idx += NT) {
        int ksg = idx >> 6, l = idx & 63, n = l & 15, q = l >> 4;
        int tile, ksl;
        if (ksg < 34)       { tile = 0; ksl = ksg; }
        else if (ksg < 68)  { tile = 1; ksl = ksg - 34; }
        else if (ksg < 100) { tile = 2; ksl = ksg - 68; }
        else                { tile = 3; ksl = ksg - 100; }
        int j = j0 + ((tile & 1) << 4) + n;
        bf16x8 v;
        if (!isf32) {
            const u16* src;
            if (tile < 2) src = (ksl < 32) ? (const u16*)recwv + (size_t)j * HD + ksl * 32 + q * 8
                                           : (const u16*)encwv + (size_t)j * NI + (ksl - 32) * 32 + q * 8;
            else          src = (const u16*)fgtwv + (size_t)j * HD + ksl * 32 + q * 8;
            v = *(const bf16x8*)src;
        } else {
            const float* src;
            if (tile < 2) src = (ksl < 32) ? (const float*)recwv + (size_t)j * HD + ksl * 32 + q * 8
                                           : (const float*)encwv + (size_t)j * NI + (ksl - 32) * 32 + q * 8;
            else          src = (const float*)fgtwv + (size_t)j * HD + ksl * 32 + q * 8;
            #pragma unroll
            for (int i = 0; i < 8; ++i) v[i] = (short)f2bf(src[i]);
        }
        *(bf16x8*)&WB[idx * 8] = v;
    }

    // ---- dec B-frags for this wave's K-quarter, kept in VGPRs (32) ----
    bf16x8 dfr[8];
    {
        int o = 16 * dt + m;         // out column
        #pragma unroll
        for (int ks = 0; ks < 8; ++ks) {
            int kb = wave * 256 + ks * 32 + quad * 8;
            if (!isf32) dfr[ks] = *(const bf16x8*)((const u16*)decwv + (size_t)o * HD + kb);
            else {
                const float* src = (const float*)decwv + (size_t)o * HD + kb;
                #pragma unroll
                for (int i = 0; i < 8; ++i) dfr[ks][i] = (short)f2bf(src[i]);
            }
        }
    }
    if (tid < CC) encbS[tid] = ldv(encbv, j0 + tid, isf32);
    if (tid < 16) decbLS[tid] = ldv(decbv, 16 * dt + tid, isf32);
    // h0 = hinit_w[:,0] + hinit_b (same for all batch rows)
    for (int e = tid; e < XR * CC; e += NT) {
        int r = e >> 5, c = e & 31;
        float v = ldv(hinitwv, j0 + c, isf32) + ldv(hinitbv, j0 + c, isf32);
        hst[e] = v;
        h0buf[(size_t)(b0 + r) * HD + j0 + c] = f2bf(v);
    }
    __syncthreads();                        // drains h0 stores to L2 (vmcnt(0))
    if (tid == 0) l2_store(myflag, 1u);     // publish h0: flag = 1

    // ---- recurrence ----
    // flag = v <=> "published h_{v-1} AND retired reads of h_{v-2}": ping-pong
    // overwrite of h_{t-1}'s storage at step t is WAR-safe once all 32 peer
    // flags reach t+1.
    for (int t = 0; t < TS; ++t) {
        if (wave == 0) wait_flags_w0(qbase, lane, (unsigned)(t + 1));
        __syncthreads();               // release waves 1-3; also orders last
                                       // step's redC out-reads before rewrite

        const u16* cur = (t & 1) ? h1buf : h0buf;
        u16*       nxt = (t & 1) ? h0buf : h1buf;

        bf16x8 a[8];
        load_a_frags(cur + (size_t)(b0 + m) * HD + wave * 256 + quad * 8, a);

        bf16x8 xf;
        if (wave < 2) {                       // enc tail A-frag from x (read-only)
            size_t xb = (size_t)(b0 + m) * (TS * NI) + (size_t)t * NI + wave * 32 + quad * 8;
            if (!isf32) xf = *(const bf16x8*)((const u16*)xv + xb);
            else {
                const float* xp = (const float*)xv + xb;
                #pragma unroll
                for (int i = 0; i < 8; ++i) xf[i] = (short)f2bf(xp[i]);
            }
        }

        f32x4 acc[5];
        #pragma unroll
        for (int tt = 0; tt < 5; ++tt) acc[tt] = (f32x4){0.f, 0.f, 0.f, 0.f};

        #pragma unroll
        for (int ks = 0; ks < 8; ++ks) {
            int kb = wave * 8 + ks;
            bf16x8 bf0 = *(const bf16x8*)&WB[((0   + kb) * 64 + lane) * 8];
            bf16x8 bf1 = *(const bf16x8*)&WB[((34  + kb) * 64 + lane) * 8];
            bf16x8 bf2 = *(const bf16x8*)&WB[((68  + kb) * 64 + lane) * 8];
            bf16x8 bf3 = *(const bf16x8*)&WB[((100 + kb) * 64 + lane) * 8];
            acc[0] = __builtin_amdgcn_mfma_f32_16x16x32_bf16(a[ks], bf0, acc[0], 0, 0, 0);
            acc[1] = __builtin_amdgcn_mfma_f32_16x16x32_bf16(a[ks], bf1, acc[1], 0, 0, 0);
            acc[2] = __builtin_amdgcn_mfma_f32_16x16x32_bf16(a[ks], bf2, acc[2], 0, 0, 0);
            acc[3] = __builtin_amdgcn_mfma_f32_16x16x32_bf16(a[ks], bf3, acc[3], 0, 0, 0);
            acc[4] = __builtin_amdgcn_mfma_f32_16x16x32_bf16(a[ks], dfr[ks], acc[4], 0, 0, 0);
        }
        if (wave < 2) {                       // enc tail (rec tiles only)
            bf16x8 e0 = *(const bf16x8*)&WB[((32 + wave) * 64 + lane) * 8];
            bf16x8 e1 = *(const bf16x8*)&WB[((34 + 32 + wave) * 64 + lane) * 8];
            acc[0] = __builtin_amdgcn_mfma_f32_16x16x32_bf16(xf, e0, acc[0], 0, 0, 0);
            acc[1] = __builtin_amdgcn_mfma_f32_16x16x32_bf16(xf, e1, acc[1], 0, 0, 0);
        }

        // C-layout 16x16: col = lane&15, row = quad*4 + reg
        #pragma unroll
        for (int tt = 0; tt < 5; ++tt) {
            #pragma unroll
            for (int r = 0; r < 4; ++r)
                redC[((wave * 5 + tt) * 16 + quad * 4 + r) * RCP + m] = acc[tt][r];
        }
        __syncthreads();

        // cross-wave K-reduction + elementwise update + h store
        for (int e = tid; e < XR * CC; e += NT) {
            int r = e >> 5, c = e & 31, tl = c >> 4, col = c & 15;
            float pr = encbS[c], pf = 0.f;
            #pragma unroll
            for (int kq = 0; kq < 4; ++kq) {
                pr += redC[((kq * 5 + tl) * 16 + r) * RCP + col];
                pf += redC[((kq * 5 + 2 + tl) * 16 + r) * RCP + col];
            }
            float fg = 1.0f / (1.0f + __expf(-pf));
            float hn = pr / (1.0f + fabsf(pr));
            float h  = hst[e];
            float hv = h + fg * (hn - h);
            hst[e] = hv;
            nxt[(size_t)(b0 + r) * HD + j0 + c] = f2bf(hv);
        }
        __syncthreads();                       // all waves' h stores acked by L2
        if (tid == 0) l2_store(myflag, (unsigned)(t + 2));   // publish h_{t+1}

        // decode h_t -> out[t-1], AFTER publish (off the inter-CU critical
        // path; redC stays valid until after next step's release barrier)
        if (slot < 4 && t > 0) {
            int r = tid >> 4, col = tid & 15;
            float o = decbLS[col];
            #pragma unroll
            for (int kq = 0; kq < 4; ++kq)
                o += redC[((kq * 5 + 4) * 16 + r) * RCP + col];
            size_t oi = (size_t)(t - 1) * (BS * NO) + (size_t)(b0 + r) * NO + 16 * dt + col;
            if (isf32) ((float*)outv)[oi] = o; else ((u16*)outv)[oi] = f2bf(o);
        }
    }

    // ---- epilogue: out[511] = decode(h_512); final hidden ----
    if (wave == 0) wait_flags_w0(qbase, lane, (unsigned)(TS + 1));
    __syncthreads();
    {
        bf16x8 a[8];
        load_a_frags(h0buf + (size_t)(b0 + m) * HD + wave * 256 + quad * 8, a);
        f32x4 ac = (f32x4){0.f, 0.f, 0.f, 0.f};
        #pragma unroll
        for (int ks = 0; ks < 8; ++ks)
            ac = __builtin_amdgcn_mfma_f32_16x16x32_bf16(a[ks], dfr[ks], ac, 0, 0, 0);
        #pragma unroll
        for (int r = 0; r < 4; ++r)
            redC[((wave * 5 + 4) * 16 + quad * 4 + r) * RCP + m] = ac[r];
        __syncthreads();
        if (slot < 4) {
            int r = tid >> 4, col = tid & 15;
            float o = decbLS[col];
            #pragma unroll
            for (int kq = 0; kq < 4; ++kq)
                o += redC[((kq * 5 + 4) * 16 + r) * RCP + col];
            size_t oi = (size_t)511 * (BS * NO) + (size_t)(b0 + r) * NO + 16 * dt + col;
            if (isf32) ((float*)outv)[oi] = o; else ((u16*)outv)[oi] = f2bf(o);
        }
        for (int e = tid; e < XR * CC; e += NT) {
            int r = e >> 5, c = e & 31;
            size_t oi = (size_t)TS * BS * NO + (size_t)(b0 + r) * HD + j0 + c;
            float v = hst[e];
            if (isf32) ((float*)outv)[oi] = v; else ((u16*)outv)[oi] = f2bf(v);
        }
    }
}

extern "C" void kernel_launch(void* const* d_in, const int* in_sizes, int n_in,
                              void* d_out, int out_size, void* d_ws, size_t ws_size,
                              hipStream_t stream) {
    (void)in_sizes; (void)n_in; (void)out_size; (void)ws_size;
    const void* xv       = d_in[0];
    const void* encwv    = d_in[1];
    const void* encbv    = d_in[2];
    const void* recwv    = d_in[3];
    const void* fgtwv    = d_in[4];
    const void* decwv    = d_in[5];
    const void* decbv    = d_in[6];
    const void* hinitwv  = d_in[7];
    const void* hinitbv  = d_in[8];
    void* outv = d_out;

    unsigned* tickets = (unsigned*)d_ws;                          // 8 x 64B-stride
    unsigned* flags   = (unsigned*)((char*)d_ws + 1024);          // 256 x 64B-stride
    u16* h0buf = (u16*)((char*)d_ws + 32768);
    u16* h1buf = h0buf + (size_t)BS * HD;

    hipMemsetAsync(d_ws, 0, 18432, stream);   // zero tickets + flags each launch

    void* args[] = { (void*)&xv, (void*)&encwv, (void*)&encbv, (void*)&recwv,
                     (void*)&fgtwv, (void*)&decwv, (void*)&decbv,
                     (void*)&hinitwv, (void*)&hinitbv,
                     (void*)&outv, (void*)&h0buf, (void*)&h1buf,
                     (void*)&tickets, (void*)&flags };
    hipLaunchCooperativeKernel((void*)arnn_xcd, dim3(NWG), dim3(NT), args, 0, stream);
}

// Round 7
// 1755.560 us; speedup vs baseline: 466.5127x; 466.5127x over previous
//
#include <hip/hip_runtime.h>

typedef unsigned short u16;

#define NWG 256
#define NT  256
#define TS  512
#define HD  1024
#define BS  128
#define NI  64
#define NO  64
#define XR  16      // batch rows per XCD
#define CC  32      // hidden cols per CU
#define RCP 17      // redC padded row stride (breaks 4-way bank conflict)

typedef __attribute__((ext_vector_type(8))) short bf16x8;
typedef __attribute__((ext_vector_type(4))) float f32x4;

__device__ __forceinline__ float bf2f(u16 u) {
    union { unsigned int i; float f; } v; v.i = ((unsigned int)u) << 16; return v.f;
}
__device__ __forceinline__ u16 f2bf(float f) {
    union { float fl; unsigned int i; } v; v.fl = f;
    unsigned int x = v.i;
    return (u16)((x + 0x7fffu + ((x >> 16) & 1u)) >> 16);  // RNE, finite inputs
}
__device__ __forceinline__ float ldv(const void* p, size_t i, bool isf32) {
    return isf32 ? ((const float*)p)[i] : bf2f(((const u16*)p)[i]);
}

// L2-executed atomic returning old value (sc0 = return-old). Round-6 finding:
// atomics are the ONLY read path that promptly observes peer-CU flag writes;
// plain sc0 load polls never see them (1.6 ms/step fallback engagement).
__device__ __forceinline__ unsigned l2_atomic_add(unsigned* p, unsigned v) {
    unsigned old;
    asm volatile("global_atomic_add %0, %1, %2, off sc0\n\t"
                 "s_waitcnt vmcnt(0)"
                 : "=&v"(old) : "v"(p), "v"(v) : "memory");
    return old;
}

// 8 A-fragments (one K-quarter) via sc0 loads (L1 bypass -> XCD L2, where peer
// CUs' write-through stores live). Proven correct for *data* in rounds 4/6.
__device__ __forceinline__ void load_a_frags(const u16* ap, bf16x8* a) {
    asm volatile(
        "global_load_dwordx4 %0, %8, off sc0\n\t"
        "global_load_dwordx4 %1, %8, off offset:64 sc0\n\t"
        "global_load_dwordx4 %2, %8, off offset:128 sc0\n\t"
        "global_load_dwordx4 %3, %8, off offset:192 sc0\n\t"
        "global_load_dwordx4 %4, %8, off offset:256 sc0\n\t"
        "global_load_dwordx4 %5, %8, off offset:320 sc0\n\t"
        "global_load_dwordx4 %6, %8, off offset:384 sc0\n\t"
        "global_load_dwordx4 %7, %8, off offset:448 sc0\n\t"
        "s_waitcnt vmcnt(0)"
        : "=&v"(a[0]), "=&v"(a[1]), "=&v"(a[2]), "=&v"(a[3]),
          "=&v"(a[4]), "=&v"(a[5]), "=&v"(a[6]), "=&v"(a[7])
        : "v"(ap) : "memory");
}

// Per-(XCD,step) counter: cnt[t] counts CUs of this XCD that published h_t.
// 64B stride so the line being polled (t) is distinct from the line being
// published (t+1) -- avoids round-4's poll/publish RMW queuing.
#define CNT_STRIDE 16   // u32s per slot = 64B

// LDS ~156KB -> exactly 1 WG/CU; cooperative launch => all 256 WGs co-resident
// => every XCD hosts exactly 32 WGs. WGs self-identify their XCD via
// s_getreg(HW_REG_XCC_ID) + per-XCD ticket; all hot-loop traffic is XCD-local.
__global__ __launch_bounds__(NT)
void arnn_xcd(const void* __restrict__ xv,
              const void* __restrict__ encwv,
              const void* __restrict__ encbv,
              const void* __restrict__ recwv,
              const void* __restrict__ fgtwv,
              const void* __restrict__ decwv,
              const void* __restrict__ decbv,
              const void* __restrict__ hinitwv,
              const void* __restrict__ hinitbv,
              void* __restrict__ outv,
              u16* __restrict__ h0buf,
              u16* __restrict__ h1buf,
              unsigned* __restrict__ tickets,
              unsigned* __restrict__ cnts)
{
    // WB: 4 n-tiles of 16 cols in MFMA B-frag lane order.
    // tile0: rec cols j0..j0+15, 34 k-steps (32 rec K=1024 + 2 enc K=64)
    // tile1: rec cols j0+16..j0+31, 34 k-steps
    // tile2/3: fgt cols, 32 k-steps. Entry: WB[(tb+ks)*64 + lane][8].
    __shared__ short WB[132 * 64 * 8];          // 135168 B
    __shared__ float redC[4 * 5 * 16 * RCP];    // 21760 B: [kq][tile(4=dec)][row][col], padded
    __shared__ float hst[XR * CC];              // fp32 master hidden slice
    __shared__ float encbS[CC];
    __shared__ float decbLS[16];
    __shared__ unsigned s_xcd, s_slot;
    __shared__ int s_f32;

    const int tid  = threadIdx.x;
    const int wave = tid >> 6;
    const int lane = tid & 63;
    const int m    = lane & 15;      // C row / A row (batch-local)
    const int quad = lane >> 4;      // k-subblock within K=32

    // ---- identify XCD, claim per-XCD CU slot ----
    if (tid == 0) {
        unsigned xcc;
        asm volatile("s_getreg_b32 %0, hwreg(HW_REG_XCC_ID, 0, 4)" : "=s"(xcc));
        xcc &= 7u;
        unsigned slot = l2_atomic_add(tickets + xcc * 16, 1u);
        s_xcd = xcc;
        s_slot = slot & 31u;
        s_f32 = 0;
    }
    __syncthreads();
    { // runtime dtype detection on rec_w raw bits (round-1 post-mortem)
        float v = bf2f(((const u16*)recwv)[tid]);
        if (!(v >= -1.0f && v <= 1.0f)) s_f32 = 1;
    }
    __syncthreads();
    const bool isf32 = (s_f32 != 0);
    const int xcd  = (int)s_xcd;
    const int slot = (int)s_slot;
    const int b0   = xcd * XR;       // this XCD's batch rows
    const int j0   = slot * CC;      // this CU's hidden cols
    const int dt   = slot & 3;       // dec tile: out cols 16dt..16dt+15
    unsigned* qcnt = cnts + (size_t)xcd * 520 * CNT_STRIDE;   // this XCD's step counters

    // ---- stage weights into LDS in B-frag order ----
    for (int idx = tid; idx < 132 * 64; idx += NT) {
        int ksg = idx >> 6, l = idx & 63, n = l & 15, q = l >> 4;
        int tile, ksl;
        if (ksg < 34)       { tile = 0; ksl = ksg; }
        else if (ksg < 68)  { tile = 1; ksl = ksg - 34; }
        else if (ksg < 100) { tile = 2; ksl = ksg - 68; }
        else                { tile = 3; ksl = ksg - 100; }
        int j = j0 + ((tile & 1) << 4) + n;
        bf16x8 v;
        if (!isf32) {
            const u16* src;
            if (tile < 2) src = (ksl < 32) ? (const u16*)recwv + (size_t)j * HD + ksl * 32 + q * 8
                                           : (const u16*)encwv + (size_t)j * NI + (ksl - 32) * 32 + q * 8;
            else          src = (const u16*)fgtwv + (size_t)j * HD + ksl * 32 + q * 8;
            v = *(const bf16x8*)src;
        } else {
            const float* src;
            if (tile < 2) src = (ksl < 32) ? (const float*)recwv + (size_t)j * HD + ksl * 32 + q * 8
                                           : (const float*)encwv + (size_t)j * NI + (ksl - 32) * 32 + q * 8;
            else          src = (const float*)fgtwv + (size_t)j * HD + ksl * 32 + q * 8;
            #pragma unroll
            for (int i = 0; i < 8; ++i) v[i] = (short)f2bf(src[i]);
        }
        *(bf16x8*)&WB[idx * 8] = v;
    }

    // ---- dec B-frags for this wave's K-quarter, kept in VGPRs (32) ----
    bf16x8 dfr[8];
    {
        int o = 16 * dt + m;         // out column
        #pragma unroll
        for (int ks = 0; ks < 8; ++ks) {
            int kb = wave * 256 + ks * 32 + quad * 8;
            if (!isf32) dfr[ks] = *(const bf16x8*)((const u16*)decwv + (size_t)o * HD + kb);
            else {
                const float* src = (const float*)decwv + (size_t)o * HD + kb;
                #pragma unroll
                for (int i = 0; i < 8; ++i) dfr[ks][i] = (short)f2bf(src[i]);
            }
        }
    }
    if (tid < CC) encbS[tid] = ldv(encbv, j0 + tid, isf32);
    if (tid < 16) decbLS[tid] = ldv(decbv, 16 * dt + tid, isf32);
    // h0 = hinit_w[:,0] + hinit_b (same for all batch rows)
    for (int e = tid; e < XR * CC; e += NT) {
        int r = e >> 5, c = e & 31;
        float v = ldv(hinitwv, j0 + c, isf32) + ldv(hinitbv, j0 + c, isf32);
        hst[e] = v;
        h0buf[(size_t)(b0 + r) * HD + j0 + c] = f2bf(v);
    }
    __syncthreads();                                  // h0 stores acked by L2 (vmcnt(0))
    if (tid == 0) l2_atomic_add(qcnt + 0 * CNT_STRIDE, 1u);   // publish h_0

    // ---- recurrence ----
    // cnt[t]==32 <=> all 32 CUs of this XCD published h_t (and thus retired
    // their reads of h_{t-2}): ping-pong overwrite of h_{t-1}'s storage at
    // step t is WAR-safe once cnt[t]==32... (reads of h_{t-1} happen in step
    // t-? ) -- identical protocol to rounds 3-6, counters instead of flags.
    for (int t = 0; t < TS; ++t) {
        if (wave == 0) {
            if (lane == 0) {   // single poller per CU; divergent-branch contained
                unsigned* p = qcnt + (size_t)t * CNT_STRIDE;
                while (l2_atomic_add(p, 0u) < 32u) __builtin_amdgcn_s_sleep(2);
            }
        }
        __syncthreads();               // release all waves; also orders last
                                       // step's redC out-reads before rewrite

        const u16* cur = (t & 1) ? h1buf : h0buf;
        u16*       nxt = (t & 1) ? h0buf : h1buf;

        bf16x8 a[8];
        load_a_frags(cur + (size_t)(b0 + m) * HD + wave * 256 + quad * 8, a);

        bf16x8 xf;
        if (wave < 2) {                       // enc tail A-frag from x (read-only)
            size_t xb = (size_t)(b0 + m) * (TS * NI) + (size_t)t * NI + wave * 32 + quad * 8;
            if (!isf32) xf = *(const bf16x8*)((const u16*)xv + xb);
            else {
                const float* xp = (const float*)xv + xb;
                #pragma unroll
                for (int i = 0; i < 8; ++i) xf[i] = (short)f2bf(xp[i]);
            }
        }

        f32x4 acc[5];
        #pragma unroll
        for (int tt = 0; tt < 5; ++tt) acc[tt] = (f32x4){0.f, 0.f, 0.f, 0.f};

        #pragma unroll
        for (int ks = 0; ks < 8; ++ks) {
            int kb = wave * 8 + ks;
            bf16x8 bf0 = *(const bf16x8*)&WB[((0   + kb) * 64 + lane) * 8];
            bf16x8 bf1 = *(const bf16x8*)&WB[((34  + kb) * 64 + lane) * 8];
            bf16x8 bf2 = *(const bf16x8*)&WB[((68  + kb) * 64 + lane) * 8];
            bf16x8 bf3 = *(const bf16x8*)&WB[((100 + kb) * 64 + lane) * 8];
            acc[0] = __builtin_amdgcn_mfma_f32_16x16x32_bf16(a[ks], bf0, acc[0], 0, 0, 0);
            acc[1] = __builtin_amdgcn_mfma_f32_16x16x32_bf16(a[ks], bf1, acc[1], 0, 0, 0);
            acc[2] = __builtin_amdgcn_mfma_f32_16x16x32_bf16(a[ks], bf2, acc[2], 0, 0, 0);
            acc[3] = __builtin_amdgcn_mfma_f32_16x16x32_bf16(a[ks], bf3, acc[3], 0, 0, 0);
            acc[4] = __builtin_amdgcn_mfma_f32_16x16x32_bf16(a[ks], dfr[ks], acc[4], 0, 0, 0);
        }
        if (wave < 2) {                       // enc tail (rec tiles only)
            bf16x8 e0 = *(const bf16x8*)&WB[((32 + wave) * 64 + lane) * 8];
            bf16x8 e1 = *(const bf16x8*)&WB[((34 + 32 + wave) * 64 + lane) * 8];
            acc[0] = __builtin_amdgcn_mfma_f32_16x16x32_bf16(xf, e0, acc[0], 0, 0, 0);
            acc[1] = __builtin_amdgcn_mfma_f32_16x16x32_bf16(xf, e1, acc[1], 0, 0, 0);
        }

        // C-layout 16x16: col = lane&15, row = quad*4 + reg
        #pragma unroll
        for (int tt = 0; tt < 5; ++tt) {
            #pragma unroll
            for (int r = 0; r < 4; ++r)
                redC[((wave * 5 + tt) * 16 + quad * 4 + r) * RCP + m] = acc[tt][r];
        }
        __syncthreads();

        // cross-wave K-reduction + elementwise update + h store
        for (int e = tid; e < XR * CC; e += NT) {
            int r = e >> 5, c = e & 31, tl = c >> 4, col = c & 15;
            float pr = encbS[c], pf = 0.f;
            #pragma unroll
            for (int kq = 0; kq < 4; ++kq) {
                pr += redC[((kq * 5 + tl) * 16 + r) * RCP + col];
                pf += redC[((kq * 5 + 2 + tl) * 16 + r) * RCP + col];
            }
            float fg = 1.0f / (1.0f + __expf(-pf));
            float hn = pr / (1.0f + fabsf(pr));
            float h  = hst[e];
            float hv = h + fg * (hn - h);
            hst[e] = hv;
            nxt[(size_t)(b0 + r) * HD + j0 + c] = f2bf(hv);
        }
        __syncthreads();                       // all waves' h stores acked by L2
        if (tid == 0) l2_atomic_add(qcnt + (size_t)(t + 1) * CNT_STRIDE, 1u);  // publish h_{t+1}

        // decode h_t -> out[t-1], AFTER publish (off the inter-CU critical
        // path; redC stays valid until after next step's release barrier)
        if (slot < 4 && t > 0) {
            int r = tid >> 4, col = tid & 15;
            float o = decbLS[col];
            #pragma unroll
            for (int kq = 0; kq < 4; ++kq)
                o += redC[((kq * 5 + 4) * 16 + r) * RCP + col];
            size_t oi = (size_t)(t - 1) * (BS * NO) + (size_t)(b0 + r) * NO + 16 * dt + col;
            if (isf32) ((float*)outv)[oi] = o; else ((u16*)outv)[oi] = f2bf(o);
        }
    }

    // ---- epilogue: out[511] = decode(h_512); final hidden ----
    if (wave == 0) {
        if (lane == 0) {
            unsigned* p = qcnt + (size_t)TS * CNT_STRIDE;
            while (l2_atomic_add(p, 0u) < 32u) __builtin_amdgcn_s_sleep(2);
        }
    }
    __syncthreads();
    {
        bf16x8 a[8];
        load_a_frags(h0buf + (size_t)(b0 + m) * HD + wave * 256 + quad * 8, a);
        f32x4 ac = (f32x4){0.f, 0.f, 0.f, 0.f};
        #pragma unroll
        for (int ks = 0; ks < 8; ++ks)
            ac = __builtin_amdgcn_mfma_f32_16x16x32_bf16(a[ks], dfr[ks], ac, 0, 0, 0);
        #pragma unroll
        for (int r = 0; r < 4; ++r)
            redC[((wave * 5 + 4) * 16 + quad * 4 + r) * RCP + m] = ac[r];
        __syncthreads();
        if (slot < 4) {
            int r = tid >> 4, col = tid & 15;
            float o = decbLS[col];
            #pragma unroll
            for (int kq = 0; kq < 4; ++kq)
                o += redC[((kq * 5 + 4) * 16 + r) * RCP + col];
            size_t oi = (size_t)511 * (BS * NO) + (size_t)(b0 + r) * NO + 16 * dt + col;
            if (isf32) ((float*)outv)[oi] = o; else ((u16*)outv)[oi] = f2bf(o);
        }
        for (int e = tid; e < XR * CC; e += NT) {
            int r = e >> 5, c = e & 31;
            size_t oi = (size_t)TS * BS * NO + (size_t)(b0 + r) * HD + j0 + c;
            float v = hst[e];
            if (isf32) ((float*)outv)[oi] = v; else ((u16*)outv)[oi] = f2bf(v);
        }
    }
}

extern "C" void kernel_launch(void* const* d_in, const int* in_sizes, int n_in,
                              void* d_out, int out_size, void* d_ws, size_t ws_size,
                              hipStream_t stream) {
    (void)in_sizes; (void)n_in; (void)out_size; (void)ws_size;
    const void* xv       = d_in[0];
    const void* encwv    = d_in[1];
    const void* encbv    = d_in[2];
    const void* recwv    = d_in[3];
    const void* fgtwv    = d_in[4];
    const void* decwv    = d_in[5];
    const void* decbv    = d_in[6];
    const void* hinitwv  = d_in[7];
    const void* hinitbv  = d_in[8];
    void* outv = d_out;

    unsigned* tickets = (unsigned*)d_ws;                       // 8 x 64B-stride
    unsigned* cnts    = (unsigned*)((char*)d_ws + 4096);       // 8 XCDs x 520 steps x 64B
    u16* h0buf = (u16*)((char*)d_ws + 524288);
    u16* h1buf = h0buf + (size_t)BS * HD;

    // zero tickets + step counters each launch (ws is re-poisoned to 0xAA)
    hipMemsetAsync(d_ws, 0, 4096 + 8 * 520 * 64, stream);

    void* args[] = { (void*)&xv, (void*)&encwv, (void*)&encbv, (void*)&recwv,
                     (void*)&fgtwv, (void*)&decwv, (void*)&decbv,
                     (void*)&hinitwv, (void*)&hinitbv,
                     (void*)&outv, (void*)&h0buf, (void*)&h1buf,
                     (void*)&tickets, (void*)&cnts };
    hipLaunchCooperativeKernel((void*)arnn_xcd, dim3(NWG), dim3(NT), args, 0, stream);
}

// Round 9
// 1627.125 us; speedup vs baseline: 503.3362x; 1.0789x over previous
//
#include <hip/hip_runtime.h>

typedef unsigned short u16;

#define NWG 256
#define NT  256
#define TS  512
#define HD  1024
#define BS  128
#define NI  64
#define NO  64
#define XR  16      // batch rows per XCD
#define CC  32      // hidden cols per CU
#define RCP 17      // redC padded row stride (breaks 4-way bank conflict)

typedef __attribute__((ext_vector_type(8))) short bf16x8;
typedef __attribute__((ext_vector_type(4))) float f32x4;

__device__ __forceinline__ float bf2f(u16 u) {
    union { unsigned int i; float f; } v; v.i = ((unsigned int)u) << 16; return v.f;
}
__device__ __forceinline__ u16 f2bf(float f) {
    union { float fl; unsigned int i; } v; v.fl = f;
    unsigned int x = v.i;
    return (u16)((x + 0x7fffu + ((x >> 16) & 1u)) >> 16);  // RNE, finite inputs
}
__device__ __forceinline__ float ldv(const void* p, size_t i, bool isf32) {
    return isf32 ? ((const float*)p)[i] : bf2f(((const u16*)p)[i]);
}

// L2-executed atomic returning old value (sc0 = return-old). Round-6 finding:
// atomics are the ONLY read path that promptly observes peer-CU flag writes;
// plain sc0 load polls never see them.
__device__ __forceinline__ unsigned l2_atomic_add(unsigned* p, unsigned v) {
    unsigned old;
    asm volatile("global_atomic_add %0, %1, %2, off sc0\n\t"
                 "s_waitcnt vmcnt(0)"
                 : "=&v"(old) : "v"(p), "v"(v) : "memory");
    return old;
}

// 8 A-fragments (one K-quarter) via sc0 loads (L1 bypass -> XCD L2, where peer
// CUs' write-through stores live). Proven correct for *data* in rounds 4/6/7.
__device__ __forceinline__ void load_a_frags(const u16* ap, bf16x8* a) {
    asm volatile(
        "global_load_dwordx4 %0, %8, off sc0\n\t"
        "global_load_dwordx4 %1, %8, off offset:64 sc0\n\t"
        "global_load_dwordx4 %2, %8, off offset:128 sc0\n\t"
        "global_load_dwordx4 %3, %8, off offset:192 sc0\n\t"
        "global_load_dwordx4 %4, %8, off offset:256 sc0\n\t"
        "global_load_dwordx4 %5, %8, off offset:320 sc0\n\t"
        "global_load_dwordx4 %6, %8, off offset:384 sc0\n\t"
        "global_load_dwordx4 %7, %8, off offset:448 sc0\n\t"
        "s_waitcnt vmcnt(0)"
        : "=&v"(a[0]), "=&v"(a[1]), "=&v"(a[2]), "=&v"(a[3]),
          "=&v"(a[4]), "=&v"(a[5]), "=&v"(a[6]), "=&v"(a[7])
        : "v"(ap) : "memory");
}

// Per-(XCD,step) counter: cnt[t] counts CUs of this XCD that published h_t.
// 64B stride so the polled line (t) differs from the published line (t+1).
#define CNT_STRIDE 16   // u32s per slot = 64B

// LDS ~156KB -> exactly 1 WG/CU (required by the per-XCD ticket scheme).
// Round-8 lesson: keep unified register usage <=256 (round-7 envelope) or the
// cooperative launch is rejected. 2 rec tiles + dec + enc frags in registers
// (~104 persistent); fgt tiles stay in LDS.
__global__ __launch_bounds__(NT)
void arnn_xcd(const void* __restrict__ xv,
              const void* __restrict__ encwv,
              const void* __restrict__ encbv,
              const void* __restrict__ recwv,
              const void* __restrict__ fgtwv,
              const void* __restrict__ decwv,
              const void* __restrict__ decbv,
              const void* __restrict__ hinitwv,
              const void* __restrict__ hinitbv,
              void* __restrict__ outv,
              u16* __restrict__ h0buf,
              u16* __restrict__ h1buf,
              unsigned* __restrict__ tickets,
              unsigned* __restrict__ cnts)
{
    // WB: 4 n-tiles of 16 cols in MFMA B-frag lane order.
    // tile0: rec cols j0..j0+15, 34 k-steps (32 rec K=1024 + 2 enc K=64)
    // tile1: rec cols j0+16..j0+31, 34 k-steps
    // tile2/3: fgt cols, 32 k-steps. Entry: WB[(tb+ks)*64 + lane][8].
    __shared__ short WB[132 * 64 * 8];          // 135168 B
    __shared__ float redC[4 * 5 * 16 * RCP];    // 21760 B: [kq][tile(4=dec)][row][col], padded
    __shared__ float hst[XR * CC];              // fp32 master hidden slice
    __shared__ float encbS[CC];
    __shared__ float decbLS[16];
    __shared__ unsigned s_xcd, s_slot;
    __shared__ int s_f32;

    const int tid  = threadIdx.x;
    const int wave = tid >> 6;
    const int lane = tid & 63;
    const int m    = lane & 15;      // C row / A row (batch-local)
    const int quad = lane >> 4;      // k-subblock within K=32

    // ---- identify XCD, claim per-XCD CU slot ----
    if (tid == 0) {
        unsigned xcc;
        asm volatile("s_getreg_b32 %0, hwreg(HW_REG_XCC_ID, 0, 4)" : "=s"(xcc));
        xcc &= 7u;
        unsigned slot = l2_atomic_add(tickets + xcc * 16, 1u);
        s_xcd = xcc;
        s_slot = slot & 31u;
        s_f32 = 0;
    }
    __syncthreads();
    { // runtime dtype detection on rec_w raw bits (round-1 post-mortem)
        float v = bf2f(((const u16*)recwv)[tid]);
        if (!(v >= -1.0f && v <= 1.0f)) s_f32 = 1;
    }
    __syncthreads();
    const bool isf32 = (s_f32 != 0);
    const int xcd  = (int)s_xcd;
    const int slot = (int)s_slot;
    const int b0   = xcd * XR;       // this XCD's batch rows
    const int j0   = slot * CC;      // this CU's hidden cols
    const int dt   = slot & 3;       // dec tile: out cols 16dt..16dt+15
    unsigned* qcnt = cnts + (size_t)xcd * 520 * CNT_STRIDE;   // this XCD's step counters

    // ---- stage weights into LDS in B-frag order ----
    for (int idx = tid; idx < 132 * 64; idx += NT) {
        int ksg = idx >> 6, l = idx & 63, n = l & 15, q = l >> 4;
        int tile, ksl;
        if (ksg < 34)       { tile = 0; ksl = ksg; }
        else if (ksg < 68)  { tile = 1; ksl = ksg - 34; }
        else if (ksg < 100) { tile = 2; ksl = ksg - 68; }
        else                { tile = 3; ksl = ksg - 100; }
        int j = j0 + ((tile & 1) << 4) + n;
        bf16x8 v;
        if (!isf32) {
            const u16* src;
            if (tile < 2) src = (ksl < 32) ? (const u16*)recwv + (size_t)j * HD + ksl * 32 + q * 8
                                           : (const u16*)encwv + (size_t)j * NI + (ksl - 32) * 32 + q * 8;
            else          src = (const u16*)fgtwv + (size_t)j * HD + ksl * 32 + q * 8;
            v = *(const bf16x8*)src;
        } else {
            const float* src;
            if (tile < 2) src = (ksl < 32) ? (const float*)recwv + (size_t)j * HD + ksl * 32 + q * 8
                                           : (const float*)encwv + (size_t)j * NI + (ksl - 32) * 32 + q * 8;
            else          src = (const float*)fgtwv + (size_t)j * HD + ksl * 32 + q * 8;
            #pragma unroll
            for (int i = 0; i < 8; ++i) v[i] = (short)f2bf(src[i]);
        }
        *(bf16x8*)&WB[idx * 8] = v;
    }
    __syncthreads();     // WB fully staged before register pull

    // ---- register-resident fragments (round-8 lesson: stay <=256 regs) ----
    // rec tiles 0,1 for this wave's K-quarter: 64 regs.
    bf16x8 Breg[2][8];
    #pragma unroll
    for (int ks = 0; ks < 8; ++ks) {
        int kb = wave * 8 + ks;
        Breg[0][ks] = *(const bf16x8*)&WB[((0  + kb) * 64 + lane) * 8];
        Breg[1][ks] = *(const bf16x8*)&WB[((34 + kb) * 64 + lane) * 8];
    }
    bf16x8 Ereg[2];      // enc-tail B-frags (waves 0,1 only): 8 regs
    if (wave < 2) {
        Ereg[0] = *(const bf16x8*)&WB[((32 + wave) * 64 + lane) * 8];
        Ereg[1] = *(const bf16x8*)&WB[((34 + 32 + wave) * 64 + lane) * 8];
    }
    // dec B-frags for this wave's K-quarter (32 regs, as round 7)
    bf16x8 dfr[8];
    {
        int o = 16 * dt + m;         // out column
        #pragma unroll
        for (int ks = 0; ks < 8; ++ks) {
            int kb = wave * 256 + ks * 32 + quad * 8;
            if (!isf32) dfr[ks] = *(const bf16x8*)((const u16*)decwv + (size_t)o * HD + kb);
            else {
                const float* src = (const float*)decwv + (size_t)o * HD + kb;
                #pragma unroll
                for (int i = 0; i < 8; ++i) dfr[ks][i] = (short)f2bf(src[i]);
            }
        }
    }
    if (tid < CC) encbS[tid] = ldv(encbv, j0 + tid, isf32);
    if (tid < 16) decbLS[tid] = ldv(decbv, 16 * dt + tid, isf32);
    // h0 = hinit_w[:,0] + hinit_b (same for all batch rows)
    for (int e = tid; e < XR * CC; e += NT) {
        int r = e >> 5, c = e & 31;
        float v = ldv(hinitwv, j0 + c, isf32) + ldv(hinitbv, j0 + c, isf32);
        hst[e] = v;
        h0buf[(size_t)(b0 + r) * HD + j0 + c] = f2bf(v);
    }
    __syncthreads();                                  // h0 stores acked by L2 (vmcnt(0))
    if (tid == 0) l2_atomic_add(qcnt + 0 * CNT_STRIDE, 1u);   // publish h_0

    // ---- recurrence ----
    // cnt[t]==32 <=> all 32 CUs of this XCD published h_t and retired their
    // h_{t-1}-buffer reads: ping-pong overwrite at step t is WAR-safe.
    for (int t = 0; t < TS; ++t) {
        f32x4 acc[5];
        #pragma unroll
        for (int tt = 0; tt < 5; ++tt) acc[tt] = (f32x4){0.f, 0.f, 0.f, 0.f};

        // enc contribution BEFORE the wait: x is read-only input, so this
        // overlaps the poll for peers instead of following it.
        if (wave < 2) {
            bf16x8 xf;
            size_t xb = (size_t)(b0 + m) * (TS * NI) + (size_t)t * NI + wave * 32 + quad * 8;
            if (!isf32) xf = *(const bf16x8*)((const u16*)xv + xb);
            else {
                const float* xp = (const float*)xv + xb;
                #pragma unroll
                for (int i = 0; i < 8; ++i) xf[i] = (short)f2bf(xp[i]);
            }
            acc[0] = __builtin_amdgcn_mfma_f32_16x16x32_bf16(xf, Ereg[0], acc[0], 0, 0, 0);
            acc[1] = __builtin_amdgcn_mfma_f32_16x16x32_bf16(xf, Ereg[1], acc[1], 0, 0, 0);
        }

        if (wave == 0 && lane == 0) {   // single poller per CU
            unsigned* p = qcnt + (size_t)t * CNT_STRIDE;
            while (l2_atomic_add(p, 0u) < 32u) __builtin_amdgcn_s_sleep(1);
        }
        __syncthreads();               // release all waves; also orders last
                                       // step's redC out-reads before rewrite

        const u16* cur = (t & 1) ? h1buf : h0buf;
        u16*       nxt = (t & 1) ? h0buf : h1buf;

        bf16x8 a[8];
        load_a_frags(cur + (size_t)(b0 + m) * HD + wave * 256 + quad * 8, a);

        #pragma unroll
        for (int ks = 0; ks < 8; ++ks) {
            int kb = wave * 8 + ks;
            bf16x8 bf2 = *(const bf16x8*)&WB[((68  + kb) * 64 + lane) * 8];
            bf16x8 bf3 = *(const bf16x8*)&WB[((100 + kb) * 64 + lane) * 8];
            acc[0] = __builtin_amdgcn_mfma_f32_16x16x32_bf16(a[ks], Breg[0][ks], acc[0], 0, 0, 0);
            acc[1] = __builtin_amdgcn_mfma_f32_16x16x32_bf16(a[ks], Breg[1][ks], acc[1], 0, 0, 0);
            acc[2] = __builtin_amdgcn_mfma_f32_16x16x32_bf16(a[ks], bf2,         acc[2], 0, 0, 0);
            acc[3] = __builtin_amdgcn_mfma_f32_16x16x32_bf16(a[ks], bf3,         acc[3], 0, 0, 0);
            acc[4] = __builtin_amdgcn_mfma_f32_16x16x32_bf16(a[ks], dfr[ks],     acc[4], 0, 0, 0);
        }

        // C-layout 16x16: col = lane&15, row = quad*4 + reg
        #pragma unroll
        for (int tt = 0; tt < 5; ++tt) {
            #pragma unroll
            for (int r = 0; r < 4; ++r)
                redC[((wave * 5 + tt) * 16 + quad * 4 + r) * RCP + m] = acc[tt][r];
        }
        __syncthreads();

        // cross-wave K-reduction + elementwise update + h store
        for (int e = tid; e < XR * CC; e += NT) {
            int r = e >> 5, c = e & 31, tl = c >> 4, col = c & 15;
            float pr = encbS[c], pf = 0.f;
            #pragma unroll
            for (int kq = 0; kq < 4; ++kq) {
                pr += redC[((kq * 5 + tl) * 16 + r) * RCP + col];
                pf += redC[((kq * 5 + 2 + tl) * 16 + r) * RCP + col];
            }
            float fg = 1.0f / (1.0f + __expf(-pf));
            float hn = pr / (1.0f + fabsf(pr));
            float h  = hst[e];
            float hv = h + fg * (hn - h);
            hst[e] = hv;
            nxt[(size_t)(b0 + r) * HD + j0 + c] = f2bf(hv);
        }
        __syncthreads();                       // all waves' h stores acked by L2
        if (tid == 0) l2_atomic_add(qcnt + (size_t)(t + 1) * CNT_STRIDE, 1u);  // publish h_{t+1}

        // decode h_t -> out[t-1], AFTER publish (off the inter-CU critical
        // path; redC stays valid until after next step's release barrier)
        if (slot < 4 && t > 0) {
            int r = tid >> 4, col = tid & 15;
            float o = decbLS[col];
            #pragma unroll
            for (int kq = 0; kq < 4; ++kq)
                o += redC[((kq * 5 + 4) * 16 + r) * RCP + col];
            size_t oi = (size_t)(t - 1) * (BS * NO) + (size_t)(b0 + r) * NO + 16 * dt + col;
            if (isf32) ((float*)outv)[oi] = o; else ((u16*)outv)[oi] = f2bf(o);
        }
    }

    // ---- epilogue: out[511] = decode(h_512); final hidden ----
    if (wave == 0 && lane == 0) {
        unsigned* p = qcnt + (size_t)TS * CNT_STRIDE;
        while (l2_atomic_add(p, 0u) < 32u) __builtin_amdgcn_s_sleep(1);
    }
    __syncthreads();
    {
        bf16x8 a[8];
        load_a_frags(h0buf + (size_t)(b0 + m) * HD + wave * 256 + quad * 8, a);
        f32x4 ac = (f32x4){0.f, 0.f, 0.f, 0.f};
        #pragma unroll
        for (int ks = 0; ks < 8; ++ks)
            ac = __builtin_amdgcn_mfma_f32_16x16x32_bf16(a[ks], dfr[ks], ac, 0, 0, 0);
        #pragma unroll
        for (int r = 0; r < 4; ++r)
            redC[((wave * 5 + 4) * 16 + quad * 4 + r) * RCP + m] = ac[r];
        __syncthreads();
        if (slot < 4) {
            int r = tid >> 4, col = tid & 15;
            float o = decbLS[col];
            #pragma unroll
            for (int kq = 0; kq < 4; ++kq)
                o += redC[((kq * 5 + 4) * 16 + r) * RCP + col];
            size_t oi = (size_t)511 * (BS * NO) + (size_t)(b0 + r) * NO + 16 * dt + col;
            if (isf32) ((float*)outv)[oi] = o; else ((u16*)outv)[oi] = f2bf(o);
        }
        for (int e = tid; e < XR * CC; e += NT) {
            int r = e >> 5, c = e & 31;
            size_t oi = (size_t)TS * BS * NO + (size_t)(b0 + r) * HD + j0 + c;
            float v = hst[e];
            if (isf32) ((float*)outv)[oi] = v; else ((u16*)outv)[oi] = f2bf(v);
        }
    }
}

extern "C" void kernel_launch(void* const* d_in, const int* in_sizes, int n_in,
                              void* d_out, int out_size, void* d_ws, size_t ws_size,
                              hipStream_t stream) {
    (void)in_sizes; (void)n_in; (void)out_size; (void)ws_size;
    const void* xv       = d_in[0];
    const void* encwv    = d_in[1];
    const void* encbv    = d_in[2];
    const void* recwv    = d_in[3];
    const void* fgtwv    = d_in[4];
    const void* decwv    = d_in[5];
    const void* decbv    = d_in[6];
    const void* hinitwv  = d_in[7];
    const void* hinitbv  = d_in[8];
    void* outv = d_out;

    unsigned* tickets = (unsigned*)d_ws;                       // 8 x 64B-stride
    unsigned* cnts    = (unsigned*)((char*)d_ws + 4096);       // 8 XCDs x 520 steps x 64B
    u16* h0buf = (u16*)((char*)d_ws + 524288);
    u16* h1buf = h0buf + (size_t)BS * HD;

    // zero tickets + step counters each launch (ws is re-poisoned to 0xAA)
    hipMemsetAsync(d_ws, 0, 4096 + 8 * 520 * 64, stream);

    void* args[] = { (void*)&xv, (void*)&encwv, (void*)&encbv, (void*)&recwv,
                     (void*)&fgtwv, (void*)&decwv, (void*)&decbv,
                     (void*)&hinitwv, (void*)&hinitbv,
                     (void*)&outv, (void*)&h0buf, (void*)&h1buf,
                     (void*)&tickets, (void*)&cnts };
    // Round-8 lesson: NEVER ignore the cooperative-launch return code (a
    // synchronous resource-rejection leaves d_out untouched -> silent zeros).
    hipError_t err = hipLaunchCooperativeKernel((void*)arnn_xcd, dim3(NWG), dim3(NT), args, 0, stream);
    if (err != hipSuccess) {
        // Fallback: plain launch. 156KB LDS -> 1 WG/CU and grid == CU count on
        // an otherwise-idle device gives de-facto co-residency.
        hipLaunchKernelGGL(arnn_xcd, dim3(NWG), dim3(NT), 0, stream,
                           xv, encwv, encbv, recwv, fgtwv, decwv, decbv,
                           hinitwv, hinitbv, outv, h0buf, h1buf, tickets, cnts);
    }
}

// Round 10
// 1604.922 us; speedup vs baseline: 510.2996x; 1.0138x over previous
//
#include <hip/hip_runtime.h>

typedef unsigned short u16;

#define NWG 256
#define NT  256
#define TS  512
#define HD  1024
#define BS  128
#define NI  64
#define NO  64
#define XR  16      // batch rows per XCD
#define CC  32      // hidden cols per CU
#define RCP 17      // redC padded row stride

typedef __attribute__((ext_vector_type(8))) short bf16x8;
typedef __attribute__((ext_vector_type(4))) float f32x4;

__device__ __forceinline__ float bf2f(u16 u) {
    union { unsigned int i; float f; } v; v.i = ((unsigned int)u) << 16; return v.f;
}
__device__ __forceinline__ u16 f2bf(float f) {
    union { float fl; unsigned int i; } v; v.fl = f;
    unsigned int x = v.i;
    return (u16)((x + 0x7fffu + ((x >> 16) & 1u)) >> 16);  // RNE, finite inputs
}
__device__ __forceinline__ float ldv(const void* p, size_t i, bool isf32) {
    return isf32 ? ((const float*)p)[i] : bf2f(((const u16*)p)[i]);
}

// L2-executed atomic returning old value (sc0 = return-old). Round-6 finding:
// atomics are the ONLY read path that promptly observes peer-CU writes.
__device__ __forceinline__ unsigned l2_atomic_add(unsigned* p, unsigned v) {
    unsigned old;
    asm volatile("global_atomic_add %0, %1, %2, off sc0\n\t"
                 "s_waitcnt vmcnt(0)"
                 : "=&v"(old) : "v"(p), "v"(v) : "memory");
    return old;
}
// Fire-and-forget atomic add (no return, no wait): used for the 32-lane
// mailbox publish -- one instruction increments 32 distinct lines.
__device__ __forceinline__ void l2_atomic_add_nr(unsigned* p, unsigned v) {
    asm volatile("global_atomic_add %0, %1, off" :: "v"(p), "v"(v) : "memory");
}

// 8 A-fragments (one K-quarter) via sc0 loads (L1 bypass -> XCD L2, where peer
// CUs' write-through stores live). Proven correct for *data* in rounds 4/6/7/9.
__device__ __forceinline__ void load_a_frags(const u16* ap, bf16x8* a) {
    asm volatile(
        "global_load_dwordx4 %0, %8, off sc0\n\t"
        "global_load_dwordx4 %1, %8, off offset:64 sc0\n\t"
        "global_load_dwordx4 %2, %8, off offset:128 sc0\n\t"
        "global_load_dwordx4 %3, %8, off offset:192 sc0\n\t"
        "global_load_dwordx4 %4, %8, off offset:256 sc0\n\t"
        "global_load_dwordx4 %5, %8, off offset:320 sc0\n\t"
        "global_load_dwordx4 %6, %8, off offset:384 sc0\n\t"
        "global_load_dwordx4 %7, %8, off offset:448 sc0\n\t"
        "s_waitcnt vmcnt(0)"
        : "=&v"(a[0]), "=&v"(a[1]), "=&v"(a[2]), "=&v"(a[3]),
          "=&v"(a[4]), "=&v"(a[5]), "=&v"(a[6]), "=&v"(a[7])
        : "v"(ap) : "memory");
}

// Per-consumer mailbox (64B stride): producers increment every consumer's
// mailbox once per published step; consumer polls ONLY its own line.
// mailbox == 32*(v) <=> all 32 CUs of the XCD published h_{v-1}.
// Round-9 lesson: a single shared poll line serializes RMWs at the L2 bank.
#define MB_STRIDE 16    // u32s = 64B

// LDS ~156KB -> exactly 1 WG/CU (required by the per-XCD ticket scheme).
// Register budget stays in the round-7/9 envelope (coop launch accepts it).
__global__ __launch_bounds__(NT)
void arnn_xcd(const void* __restrict__ xv,
              const void* __restrict__ encwv,
              const void* __restrict__ encbv,
              const void* __restrict__ recwv,
              const void* __restrict__ fgtwv,
              const void* __restrict__ decwv,
              const void* __restrict__ decbv,
              const void* __restrict__ hinitwv,
              const void* __restrict__ hinitbv,
              void* __restrict__ outv,
              u16* __restrict__ h0buf,
              u16* __restrict__ h1buf,
              unsigned* __restrict__ tickets,
              unsigned* __restrict__ mboxes)
{
    // WB: 4 n-tiles of 16 cols in MFMA B-frag lane order.
    // tile0: rec cols j0..j0+15, 34 k-steps (32 rec K=1024 + 2 enc K=64)
    // tile1: rec cols j0+16..j0+31, 34 k-steps
    // tile2/3: fgt cols, 32 k-steps. Entry: WB[(tb+ks)*64 + lane][8].
    __shared__ short WB[132 * 64 * 8];          // 135168 B
    __shared__ float redC[4 * 5 * 16 * RCP];    // 21760 B: [kq][tile(4=dec)][row][col]
    __shared__ float hst[XR * CC];              // fp32 master hidden slice
    __shared__ float encbS[CC];
    __shared__ float decbLS[16];
    __shared__ unsigned s_xcd, s_slot;
    __shared__ int s_f32;

    const int tid  = threadIdx.x;
    const int wave = tid >> 6;
    const int lane = tid & 63;
    const int m    = lane & 15;      // C row / A row (batch-local)
    const int quad = lane >> 4;      // k-subblock within K=32

    // ---- identify XCD, claim per-XCD CU slot ----
    if (tid == 0) {
        unsigned xcc;
        asm volatile("s_getreg_b32 %0, hwreg(HW_REG_XCC_ID, 0, 4)" : "=s"(xcc));
        xcc &= 7u;
        unsigned slot = l2_atomic_add(tickets + xcc * 16, 1u);
        s_xcd = xcc;
        s_slot = slot & 31u;
        s_f32 = 0;
    }
    __syncthreads();
    { // runtime dtype detection on rec_w raw bits (round-1 post-mortem)
        float v = bf2f(((const u16*)recwv)[tid]);
        if (!(v >= -1.0f && v <= 1.0f)) s_f32 = 1;
    }
    __syncthreads();
    const bool isf32 = (s_f32 != 0);
    const int xcd  = (int)s_xcd;
    const int slot = (int)s_slot;
    const int b0   = xcd * XR;       // this XCD's batch rows
    const int j0   = slot * CC;      // this CU's hidden cols
    const int dt   = slot & 3;       // dec tile: out cols 16dt..16dt+15
    unsigned* mbX   = mboxes + (size_t)xcd * 32 * MB_STRIDE;  // XCD's 32 mailboxes
    unsigned* mbOwn = mbX + slot * MB_STRIDE;                 // this CU's mailbox

    // ---- stage weights into LDS in B-frag order ----
    for (int idx = tid; idx < 132 * 64; idx += NT) {
        int ksg = idx >> 6, l = idx & 63, n = l & 15, q = l >> 4;
        int tile, ksl;
        if (ksg < 34)       { tile = 0; ksl = ksg; }
        else if (ksg < 68)  { tile = 1; ksl = ksg - 34; }
        else if (ksg < 100) { tile = 2; ksl = ksg - 68; }
        else                { tile = 3; ksl = ksg - 100; }
        int j = j0 + ((tile & 1) << 4) + n;
        bf16x8 v;
        if (!isf32) {
            const u16* src;
            if (tile < 2) src = (ksl < 32) ? (const u16*)recwv + (size_t)j * HD + ksl * 32 + q * 8
                                           : (const u16*)encwv + (size_t)j * NI + (ksl - 32) * 32 + q * 8;
            else          src = (const u16*)fgtwv + (size_t)j * HD + ksl * 32 + q * 8;
            v = *(const bf16x8*)src;
        } else {
            const float* src;
            if (tile < 2) src = (ksl < 32) ? (const float*)recwv + (size_t)j * HD + ksl * 32 + q * 8
                                           : (const float*)encwv + (size_t)j * NI + (ksl - 32) * 32 + q * 8;
            else          src = (const float*)fgtwv + (size_t)j * HD + ksl * 32 + q * 8;
            #pragma unroll
            for (int i = 0; i < 8; ++i) v[i] = (short)f2bf(src[i]);
        }
        *(bf16x8*)&WB[idx * 8] = v;
    }
    __syncthreads();     // WB fully staged before register pull

    // ---- register-resident fragments (round-8 lesson: stay <=256 regs) ----
    bf16x8 Breg[2][8];   // rec tiles 0,1 for this wave's K-quarter: 64 regs
    #pragma unroll
    for (int ks = 0; ks < 8; ++ks) {
        int kb = wave * 8 + ks;
        Breg[0][ks] = *(const bf16x8*)&WB[((0  + kb) * 64 + lane) * 8];
        Breg[1][ks] = *(const bf16x8*)&WB[((34 + kb) * 64 + lane) * 8];
    }
    bf16x8 Ereg[2];      // enc-tail B-frags (waves 0,1 only): 8 regs
    if (wave < 2) {
        Ereg[0] = *(const bf16x8*)&WB[((32 + wave) * 64 + lane) * 8];
        Ereg[1] = *(const bf16x8*)&WB[((34 + 32 + wave) * 64 + lane) * 8];
    }
    bf16x8 dfr[8];       // dec B-frags for this wave's K-quarter: 32 regs
    {
        int o = 16 * dt + m;         // out column
        #pragma unroll
        for (int ks = 0; ks < 8; ++ks) {
            int kb = wave * 256 + ks * 32 + quad * 8;
            if (!isf32) dfr[ks] = *(const bf16x8*)((const u16*)decwv + (size_t)o * HD + kb);
            else {
                const float* src = (const float*)decwv + (size_t)o * HD + kb;
                #pragma unroll
                for (int i = 0; i < 8; ++i) dfr[ks][i] = (short)f2bf(src[i]);
            }
        }
    }
    if (tid < CC) encbS[tid] = ldv(encbv, j0 + tid, isf32);
    if (tid < 16) decbLS[tid] = ldv(decbv, 16 * dt + tid, isf32);
    // h0 = hinit_w[:,0] + hinit_b (same for all batch rows)
    for (int e = tid; e < XR * CC; e += NT) {
        int r = e >> 5, c = e & 31;
        float v = ldv(hinitwv, j0 + c, isf32) + ldv(hinitbv, j0 + c, isf32);
        hst[e] = v;
        h0buf[(size_t)(b0 + r) * HD + j0 + c] = f2bf(v);
    }
    __syncthreads();                             // h0 stores acked by L2 (vmcnt(0))
    if (tid < 32) l2_atomic_add_nr(mbX + tid * MB_STRIDE, 1u);   // publish h_0 to all peers

    // ---- recurrence ----
    // mbOwn >= 32*(t+1) <=> all 32 CUs of this XCD published h_t and retired
    // their h_{t-1}-buffer reads: ping-pong overwrite at step t is WAR-safe.
    for (int t = 0; t < TS; ++t) {
        f32x4 acc[5];
        #pragma unroll
        for (int tt = 0; tt < 5; ++tt) acc[tt] = (f32x4){0.f, 0.f, 0.f, 0.f};

        // enc contribution BEFORE the wait (x is read-only input)
        if (wave < 2) {
            bf16x8 xf;
            size_t xb = (size_t)(b0 + m) * (TS * NI) + (size_t)t * NI + wave * 32 + quad * 8;
            if (!isf32) xf = *(const bf16x8*)((const u16*)xv + xb);
            else {
                const float* xp = (const float*)xv + xb;
                #pragma unroll
                for (int i = 0; i < 8; ++i) xf[i] = (short)f2bf(xp[i]);
            }
            acc[0] = __builtin_amdgcn_mfma_f32_16x16x32_bf16(xf, Ereg[0], acc[0], 0, 0, 0);
            acc[1] = __builtin_amdgcn_mfma_f32_16x16x32_bf16(xf, Ereg[1], acc[1], 0, 0, 0);
        }

        // Per-wave poll on own mailbox (private line -> no RMW queueing; no
        // release barrier needed -- each wave proceeds the moment data is ready)
        if (lane == 0) {
            unsigned target = 32u * (unsigned)(t + 1);
            while (l2_atomic_add(mbOwn, 0u) < target) {}
        }

        const u16* cur = (t & 1) ? h1buf : h0buf;
        u16*       nxt = (t & 1) ? h0buf : h1buf;

        bf16x8 a[8];
        load_a_frags(cur + (size_t)(b0 + m) * HD + wave * 256 + quad * 8, a);

        #pragma unroll
        for (int ks = 0; ks < 8; ++ks) {
            int kb = wave * 8 + ks;
            bf16x8 bf2 = *(const bf16x8*)&WB[((68  + kb) * 64 + lane) * 8];
            bf16x8 bf3 = *(const bf16x8*)&WB[((100 + kb) * 64 + lane) * 8];
            acc[0] = __builtin_amdgcn_mfma_f32_16x16x32_bf16(a[ks], Breg[0][ks], acc[0], 0, 0, 0);
            acc[1] = __builtin_amdgcn_mfma_f32_16x16x32_bf16(a[ks], Breg[1][ks], acc[1], 0, 0, 0);
            acc[2] = __builtin_amdgcn_mfma_f32_16x16x32_bf16(a[ks], bf2,         acc[2], 0, 0, 0);
            acc[3] = __builtin_amdgcn_mfma_f32_16x16x32_bf16(a[ks], bf3,         acc[3], 0, 0, 0);
            acc[4] = __builtin_amdgcn_mfma_f32_16x16x32_bf16(a[ks], dfr[ks],     acc[4], 0, 0, 0);
        }

        // C-layout 16x16: col = lane&15, row = quad*4 + reg
        #pragma unroll
        for (int tt = 0; tt < 5; ++tt) {
            #pragma unroll
            for (int r = 0; r < 4; ++r)
                redC[((wave * 5 + tt) * 16 + quad * 4 + r) * RCP + m] = acc[tt][r];
        }
        __syncthreads();

        // decode h_t -> out[t-1] (moved INTO this phase: its redC reads now
        // complete before the pre-publish barrier, so no post-publish redC
        // hazard -- which is what allowed removing the release barrier)
        if (slot < 4 && t > 0) {
            int r = tid >> 4, col = tid & 15;
            float o = decbLS[col];
            #pragma unroll
            for (int kq = 0; kq < 4; ++kq)
                o += redC[((kq * 5 + 4) * 16 + r) * RCP + col];
            size_t oi = (size_t)(t - 1) * (BS * NO) + (size_t)(b0 + r) * NO + 16 * dt + col;
            if (isf32) ((float*)outv)[oi] = o; else ((u16*)outv)[oi] = f2bf(o);
        }
        // cross-wave K-reduction + elementwise update + h store
        for (int e = tid; e < XR * CC; e += NT) {
            int r = e >> 5, c = e & 31, tl = c >> 4, col = c & 15;
            float pr = encbS[c], pf = 0.f;
            #pragma unroll
            for (int kq = 0; kq < 4; ++kq) {
                pr += redC[((kq * 5 + tl) * 16 + r) * RCP + col];
                pf += redC[((kq * 5 + 2 + tl) * 16 + r) * RCP + col];
            }
            float fg = 1.0f / (1.0f + __expf(-pf));
            float hn = pr / (1.0f + fabsf(pr));
            float h  = hst[e];
            float hv = h + fg * (hn - h);
            hst[e] = hv;
            nxt[(size_t)(b0 + r) * HD + j0 + c] = f2bf(hv);
        }
        __syncthreads();                       // all waves' h (and out) stores acked by L2
        if (tid < 32) l2_atomic_add_nr(mbX + tid * MB_STRIDE, 1u);   // publish h_{t+1}
    }

    // ---- epilogue: out[511] = decode(h_512); final hidden ----
    if (lane == 0) {
        unsigned target = 32u * (unsigned)(TS + 1);
        while (l2_atomic_add(mbOwn, 0u) < target) {}
    }
    {
        bf16x8 a[8];
        load_a_frags(h0buf + (size_t)(b0 + m) * HD + wave * 256 + quad * 8, a);
        f32x4 ac = (f32x4){0.f, 0.f, 0.f, 0.f};
        #pragma unroll
        for (int ks = 0; ks < 8; ++ks)
            ac = __builtin_amdgcn_mfma_f32_16x16x32_bf16(a[ks], dfr[ks], ac, 0, 0, 0);
        #pragma unroll
        for (int r = 0; r < 4; ++r)
            redC[((wave * 5 + 4) * 16 + quad * 4 + r) * RCP + m] = ac[r];
        __syncthreads();
        if (slot < 4) {
            int r = tid >> 4, col = tid & 15;
            float o = decbLS[col];
            #pragma unroll
            for (int kq = 0; kq < 4; ++kq)
                o += redC[((kq * 5 + 4) * 16 + r) * RCP + col];
            size_t oi = (size_t)511 * (BS * NO) + (size_t)(b0 + r) * NO + 16 * dt + col;
            if (isf32) ((float*)outv)[oi] = o; else ((u16*)outv)[oi] = f2bf(o);
        }
        for (int e = tid; e < XR * CC; e += NT) {
            int r = e >> 5, c = e & 31;
            size_t oi = (size_t)TS * BS * NO + (size_t)(b0 + r) * HD + j0 + c;
            float v = hst[e];
            if (isf32) ((float*)outv)[oi] = v; else ((u16*)outv)[oi] = f2bf(v);
        }
    }
}

extern "C" void kernel_launch(void* const* d_in, const int* in_sizes, int n_in,
                              void* d_out, int out_size, void* d_ws, size_t ws_size,
                              hipStream_t stream) {
    (void)in_sizes; (void)n_in; (void)out_size; (void)ws_size;
    const void* xv       = d_in[0];
    const void* encwv    = d_in[1];
    const void* encbv    = d_in[2];
    const void* recwv    = d_in[3];
    const void* fgtwv    = d_in[4];
    const void* decwv    = d_in[5];
    const void* decbv    = d_in[6];
    const void* hinitwv  = d_in[7];
    const void* hinitbv  = d_in[8];
    void* outv = d_out;

    unsigned* tickets = (unsigned*)d_ws;                       // 8 x 64B-stride
    unsigned* mboxes  = (unsigned*)((char*)d_ws + 4096);       // 8 XCDs x 32 CUs x 64B
    u16* h0buf = (u16*)((char*)d_ws + 524288);
    u16* h1buf = h0buf + (size_t)BS * HD;

    // zero tickets + mailboxes each launch (ws is re-poisoned to 0xAA)
    hipMemsetAsync(d_ws, 0, 4096 + 8 * 32 * 64, stream);

    void* args[] = { (void*)&xv, (void*)&encwv, (void*)&encbv, (void*)&recwv,
                     (void*)&fgtwv, (void*)&decwv, (void*)&decbv,
                     (void*)&hinitwv, (void*)&hinitbv,
                     (void*)&outv, (void*)&h0buf, (void*)&h1buf,
                     (void*)&tickets, (void*)&mboxes };
    // Round-8 lesson: NEVER ignore the cooperative-launch return code.
    hipError_t err = hipLaunchCooperativeKernel((void*)arnn_xcd, dim3(NWG), dim3(NT), args, 0, stream);
    if (err != hipSuccess) {
        hipLaunchKernelGGL(arnn_xcd, dim3(NWG), dim3(NT), 0, stream,
                           xv, encwv, encbv, recwv, fgtwv, decwv, decbv,
                           hinitwv, hinitbv, outv, h0buf, h1buf, tickets, mboxes);
    }
}